// Round 5
// baseline (28.902 us; speedup 1.0000x reference)
//
#include <hip/hip_runtime.h>
#include <math.h>

// RelativeDepthLoss — H=W=64, N=4096, f32 in, f32 scalar out.
// R2-proven shell: hipMemsetAsync(16B) + ONE kernel, 256 blocks x 256 thr, 1 blk/CU.
//   block b: i-strip = pixels [16b,16b+16), all in image row ri=b>>2.
//   wave w: i-quad iq=16b+4w..+3 (cols ci0..ci0+3). lane l: image row l (64 j's).
//   => distance row dr=|ri-l| is CONSTANT PER LANE. The 72 reciprocal distances
//      rt[q] = 1/(sqrt(dr^2+(q-6-ci0)^2)+0.001) are COMPUTED IN REGISTERS
//      (v_sqrt_f32+v_rcp_f32, ~1150cyc one-time) — no LDS table (R2: LDS-bound),
//      no global table (R4: lane-scattered loads, +5us).
//   Inner (fully unrolled 64x, rt indices compile-time): 1 ds_read_b64 (djw,
//   stride-65-float2 = 4-touch/bank structural floor) + 12 VALU per 4 pairs
//   (fabsf folds to input modifier).
//   Grad: sobel of (pred-gt) by linearity (16 px/block, LDS). Finalize: atomics
//   + counter, last block writes out. ws[0..3] re-zeroed by memset every call.

#define IDX(j) ((j) + ((j) >> 6))   // djw padding: +1 float2 per 64 (stride 65)

__global__ __launch_bounds__(256) void fused(const float* __restrict__ pred,
                                             const float* __restrict__ gt,
                                             const int* __restrict__ mask,
                                             float* __restrict__ ws,
                                             float* __restrict__ out) {
    __shared__ float2 djw[4096 + 64];
    __shared__ float  red[12];

    const int t = threadIdx.x;
    const int b = blockIdx.x;

    // ---- stage d = pred-gt, w = mask (float4 loads, 16 px/thread) ----
    for (int m = 0; m < 4; ++m) {
        const int q = (m << 8) + t;                    // float4 index
        const float4 p4 = ((const float4*)pred)[q];
        const float4 g4 = ((const float4*)gt)[q];
        const int4   m4 = ((const int4*)mask)[q];
        const int o = IDX(q << 2);                     // same 64-group for all 4
        djw[o + 0] = make_float2(p4.x - g4.x, m4.x ? 1.f : 0.f);
        djw[o + 1] = make_float2(p4.y - g4.y, m4.y ? 1.f : 0.f);
        djw[o + 2] = make_float2(p4.z - g4.z, m4.z ? 1.f : 0.f);
        djw[o + 3] = make_float2(p4.w - g4.w, m4.w ? 1.f : 0.f);
    }

    // ---- per-lane reciprocal-distance registers (pure VALU, no memory) ----
    const int wv  = t >> 6;
    const int l   = t & 63;                            // lane = j image row
    const int iq  = (b << 4) + (wv << 2);              // wave's i-quad base
    const int ri  = b >> 2;
    const int ci0 = iq & 63;
    const int row = (ri >= l) ? (ri - l) : (l - ri);   // lane-constant dr

    float rt[72];                                      // rt[q] <-> dc = q - 6 - ci0
    {
        const float dr2 = (float)(row * row);
        float dc = (float)(-6 - ci0);
#pragma unroll
        for (int q = 0; q < 72; ++q) {
            const float s = __builtin_amdgcn_sqrtf(fmaf(dc, dc, dr2));
            rt[q] = __builtin_amdgcn_rcpf(s + 0.001f);
            dc += 1.0f;
        }
    }
    __syncthreads();

    // ---- pairwise: 4 i's x 64 j's per lane, fully unrolled ----
    const float2 dwi0 = djw[IDX(iq + 0)];              // broadcast reads (free)
    const float2 dwi1 = djw[IDX(iq + 1)];
    const float2 dwi2 = djw[IDX(iq + 2)];
    const float2 dwi3 = djw[IDX(iq + 3)];
    const float2* dp = &djw[65 * l];                   // IDX(64*l)

    float acc0 = 0.f, acc1 = 0.f, acc2 = 0.f, acc3 = 0.f;
#pragma unroll
    for (int cj = 0; cj < 64; ++cj) {                  // rt indices compile-time
        const float2 dw = dp[cj];
        const float  w  = dw.y;
        acc0 = fmaf(fabsf(dwi0.x - dw.x), rt[cj + 6] * w, acc0);
        acc1 = fmaf(fabsf(dwi1.x - dw.x), rt[cj + 5] * w, acc1);
        acc2 = fmaf(fabsf(dwi2.x - dw.x), rt[cj + 4] * w, acc2);
        acc3 = fmaf(fabsf(dwi3.x - dw.x), rt[cj + 3] * w, acc3);
    }
    float acc = dwi0.y * acc0 + dwi1.y * acc1 + dwi2.y * acc2 + dwi3.y * acc3;

    // ---- sobel grad for this block's 16 pixels (zero-pad edges) ----
    float gp = 0.f, mp = 0.f;
    if (t < 16) {
        const int k = (b << 4) + t;
        const int r = k >> 6, c = k & 63;
        const float x00 = (r > 0  && c > 0 ) ? djw[IDX(k - 65)].x : 0.f;
        const float x01 = (r > 0           ) ? djw[IDX(k - 64)].x : 0.f;
        const float x02 = (r > 0  && c < 63) ? djw[IDX(k - 63)].x : 0.f;
        const float x10 = (          c > 0 ) ? djw[IDX(k - 1 )].x : 0.f;
        const float x12 = (          c < 63) ? djw[IDX(k + 1 )].x : 0.f;
        const float x20 = (r < 63 && c > 0 ) ? djw[IDX(k + 63)].x : 0.f;
        const float x21 = (r < 63          ) ? djw[IDX(k + 64)].x : 0.f;
        const float x22 = (r < 63 && c < 63) ? djw[IDX(k + 65)].x : 0.f;
        const float gx = (x02 - x00) + 2.f * (x12 - x10) + (x22 - x20);
        const float gy = (x20 - x00) + 2.f * (x21 - x01) + (x22 - x02);
        mp = djw[IDX(k)].y;
        gp = mp * (fabsf(gx) + fabsf(gy));
    }

    // ---- block reduction (3 values) ----
    for (int off = 32; off > 0; off >>= 1) {
        acc += __shfl_down(acc, off, 64);
        gp  += __shfl_down(gp,  off, 64);
        mp  += __shfl_down(mp,  off, 64);
    }
    if (l == 0) { red[wv] = acc; red[4 + wv] = gp; red[8 + wv] = mp; }
    __syncthreads();

    // ---- publish; last-finished block finalizes ----
    if (t == 0) {
        atomicAdd(&ws[0], red[0] + red[1] + red[2]  + red[3]);
        atomicAdd(&ws[1], red[4] + red[5] + red[6]  + red[7]);
        atomicAdd(&ws[2], red[8] + red[9] + red[10] + red[11]);
        __threadfence();
        const unsigned old = atomicAdd((unsigned*)(ws + 3), 1u);
        if (old == 255u) {
            const float pair = atomicAdd(&ws[0], 0.f);
            const float gnum = atomicAdd(&ws[1], 0.f);
            const float msum = atomicAdd(&ws[2], 0.f);
            const float grad_loss = gnum / msum;
            const float pair_loss = pair / sqrtf(msum * msum + 1e-5f);
            out[0] = logf(0.5f * grad_loss + 0.5f * pair_loss + 1.f);
        }
    }
}

extern "C" void kernel_launch(void* const* d_in, const int* in_sizes, int n_in,
                              void* d_out, int out_size, void* d_ws, size_t ws_size,
                              hipStream_t stream) {
    const float* pred = (const float*)d_in[0];
    const float* gt   = (const float*)d_in[1];
    const int*   msk  = (const int*)d_in[2];
    float* ws  = (float*)d_ws;
    float* out = (float*)d_out;

    hipMemsetAsync(d_ws, 0, 16, stream);   // zero pair/grad/mask accumulators + counter
    fused<<<256, 256, 0, stream>>>(pred, gt, msk, ws, out);
}

// Round 6
// 17.580 us; speedup vs baseline: 1.6440x; 1.6440x over previous
//
#include <hip/hip_runtime.h>
#include <math.h>

// RelativeDepthLoss — H=W=64, N=4096, f32 in, f32 scalar out.
// ONE kernel, NO memset node. 256 blocks x 256 thr (1 blk/CU).
//   block b: i-strip = pixels [16b,16b+16), all in image row ri=b>>2.
//   wave w: i-quad iq=16b+4w..+3 (cols ci0..ci0+3). lane l: image row l (64 j's)
//   => dr=|ri-l| is LANE-CONSTANT.
//   Reciprocal distances from an LDS table tbl[64][129] (stride 129 odd =>
//   bank=(dr+c)%32, conflict-free), read via a SCALAR ROLLING WINDOW h0..h3:
//   at column cj the 4 accs need trow[cj..cj-3], 3 of which are prior reads.
//   Inner loop per 4 pairs: 1 ds_read_b32 + 1 ds_read_b64 + 12 VALU, only
//   scalar carries — no indexable local array (R4/R5 lesson: rt[72] array
//   went to scratch; rule #20).
//   Grad: sobel of (pred-gt) by linearity (16 px/block, from LDS).
//   Finalize: per-block slots ws[4+b]/[260+b]/[516+b] (plain store + fence),
//   mod-256 ticket counter at ws[0] — works from ANY counter start value
//   (poison 0xAA ok): each call does exactly 256 increments and exactly one
//   block sees (old&255)==255. Identical work every call, no state required.

#define IDX(j) ((j) + ((j) >> 6))   // djw padding: +1 float2 per 64 (stride 65)

__global__ __launch_bounds__(256) void fused(const float* __restrict__ pred,
                                             const float* __restrict__ gt,
                                             const int* __restrict__ mask,
                                             float* __restrict__ ws,
                                             float* __restrict__ out) {
    __shared__ float2 djw[4096 + 64];
    __shared__ float  tbl[64 * 129];
    __shared__ float  red[12];
    __shared__ int    lastFlag;

    const int t = threadIdx.x;
    const int b = blockIdx.x;

    // ---- stage d = pred-gt, w = mask (float4 loads, 16 px/thread) ----
    for (int m = 0; m < 4; ++m) {
        const int q = (m << 8) + t;                    // float4 index
        const float4 p4 = ((const float4*)pred)[q];
        const float4 g4 = ((const float4*)gt)[q];
        const int4   m4 = ((const int4*)mask)[q];
        const int o = IDX(q << 2);                     // same 64-group for all 4
        djw[o + 0] = make_float2(p4.x - g4.x, m4.x ? 1.f : 0.f);
        djw[o + 1] = make_float2(p4.y - g4.y, m4.y ? 1.f : 0.f);
        djw[o + 2] = make_float2(p4.z - g4.z, m4.z ? 1.f : 0.f);
        djw[o + 3] = make_float2(p4.w - g4.w, m4.w ? 1.f : 0.f);
    }

    // ---- LDS reciprocal-distance table: tbl[dr*129 + (dc+64)] ----
    {
        const int   r  = t >> 2;                       // 4 threads per row
        const float r2 = (float)(r * r);
        for (int c = (t & 3); c < 129; c += 4) {
            const float dc = (float)(c - 64);
            tbl[r * 129 + c] =
                __builtin_amdgcn_rcpf(__builtin_amdgcn_sqrtf(fmaf(dc, dc, r2)) + 0.001f);
        }
    }
    __syncthreads();

    // ---- pairwise: 4 i's x 64 j's per lane, rolling table window ----
    const int wv  = t >> 6;
    const int l   = t & 63;                            // lane = j image row
    const int iq  = (b << 4) + (wv << 2);              // wave's i-quad base
    const int ri  = b >> 2;
    const int ci0 = iq & 63;
    const int dr  = (ri >= l) ? (ri - l) : (l - ri);   // lane-constant

    const float*  trowB = &tbl[dr * 129 + 64 - ci0];   // c(cj,k) = trowB[cj-k]
    const float2* dp    = &djw[65 * l];                // IDX(64*l)
    const float2  dwi0  = djw[IDX(iq + 0)];            // broadcast reads
    const float2  dwi1  = djw[IDX(iq + 1)];
    const float2  dwi2  = djw[IDX(iq + 2)];
    const float2  dwi3  = djw[IDX(iq + 3)];

    float h1 = trowB[-1], h2 = trowB[-2], h3 = trowB[-3];  // prime window
    float acc0 = 0.f, acc1 = 0.f, acc2 = 0.f, acc3 = 0.f;
#pragma unroll
    for (int cj = 0; cj < 64; ++cj) {
        const float  h0 = trowB[cj];
        const float2 dw = dp[cj];
        const float  w  = dw.y;
        acc0 = fmaf(fabsf(dwi0.x - dw.x), h0 * w, acc0);
        acc1 = fmaf(fabsf(dwi1.x - dw.x), h1 * w, acc1);
        acc2 = fmaf(fabsf(dwi2.x - dw.x), h2 * w, acc2);
        acc3 = fmaf(fabsf(dwi3.x - dw.x), h3 * w, acc3);
        h3 = h2; h2 = h1; h1 = h0;                     // renames after unroll
    }
    float acc = dwi0.y * acc0 + dwi1.y * acc1 + dwi2.y * acc2 + dwi3.y * acc3;

    // ---- sobel grad for this block's 16 pixels (zero-pad edges) ----
    float gp = 0.f, mp = 0.f;
    if (t < 16) {
        const int k = (b << 4) + t;
        const int r = k >> 6, c = k & 63;
        const float x00 = (r > 0  && c > 0 ) ? djw[IDX(k - 65)].x : 0.f;
        const float x01 = (r > 0           ) ? djw[IDX(k - 64)].x : 0.f;
        const float x02 = (r > 0  && c < 63) ? djw[IDX(k - 63)].x : 0.f;
        const float x10 = (          c > 0 ) ? djw[IDX(k - 1 )].x : 0.f;
        const float x12 = (          c < 63) ? djw[IDX(k + 1 )].x : 0.f;
        const float x20 = (r < 63 && c > 0 ) ? djw[IDX(k + 63)].x : 0.f;
        const float x21 = (r < 63          ) ? djw[IDX(k + 64)].x : 0.f;
        const float x22 = (r < 63 && c < 63) ? djw[IDX(k + 65)].x : 0.f;
        const float gx = (x02 - x00) + 2.f * (x12 - x10) + (x22 - x20);
        const float gy = (x20 - x00) + 2.f * (x21 - x01) + (x22 - x02);
        mp = djw[IDX(k)].y;
        gp = mp * (fabsf(gx) + fabsf(gy));
    }

    // ---- block reduction (3 values) ----
    for (int off = 32; off > 0; off >>= 1) {
        acc += __shfl_down(acc, off, 64);
        gp  += __shfl_down(gp,  off, 64);
        mp  += __shfl_down(mp,  off, 64);
    }
    if (l == 0) { red[wv] = acc; red[4 + wv] = gp; red[8 + wv] = mp; }
    __syncthreads();

    // ---- publish partials (plain stores) + ticket; last block finalizes ----
    if (t == 0) {
        ws[4   + b] = red[0] + red[1] + red[2]  + red[3];
        ws[260 + b] = red[4] + red[5] + red[6]  + red[7];
        ws[516 + b] = red[8] + red[9] + red[10] + red[11];
        __threadfence();                                // release
        const unsigned old = atomicAdd((unsigned*)ws, 1u);
        lastFlag = ((old & 255u) == 255u) ? 1 : 0;
    }
    __syncthreads();

    if (lastFlag) {
        __threadfence();                                // acquire
        float p = atomicAdd(&ws[4   + t], 0.f);         // coherent reads
        float g = atomicAdd(&ws[260 + t], 0.f);
        float m = atomicAdd(&ws[516 + t], 0.f);
        for (int off = 32; off > 0; off >>= 1) {
            p += __shfl_down(p, off, 64);
            g += __shfl_down(g, off, 64);
            m += __shfl_down(m, off, 64);
        }
        __syncthreads();                                // red[] reuse guard
        if ((t & 63) == 0) { red[t >> 6] = p; red[4 + (t >> 6)] = g; red[8 + (t >> 6)] = m; }
        __syncthreads();
        if (t == 0) {
            p = red[0] + red[1] + red[2]  + red[3];
            g = red[4] + red[5] + red[6]  + red[7];
            m = red[8] + red[9] + red[10] + red[11];
            const float grad_loss = g / m;
            const float pair_loss = p / sqrtf(m * m + 1e-5f);
            out[0] = logf(0.5f * grad_loss + 0.5f * pair_loss + 1.f);
        }
    }
}

extern "C" void kernel_launch(void* const* d_in, const int* in_sizes, int n_in,
                              void* d_out, int out_size, void* d_ws, size_t ws_size,
                              hipStream_t stream) {
    const float* pred = (const float*)d_in[0];
    const float* gt   = (const float*)d_in[1];
    const int*   msk  = (const int*)d_in[2];
    float* ws  = (float*)d_ws;
    float* out = (float*)d_out;

    fused<<<256, 256, 0, stream>>>(pred, gt, msk, ws, out);
}